// Round 2
// baseline (4508.422 us; speedup 1.0000x reference)
//
#include <hip/hip_runtime.h>

#define E_EDGES 320000
#define NF 20

__device__ __forceinline__ float selu_f(float x) {
    const float scale = 1.0507009873554805f;
    const float alpha = 1.6732632423543772f;
    return x > 0.f ? scale * x : scale * alpha * (__expf(x) - 1.f);
}

// B[e][o] = sum_f h[e][f] * W1[20+f][o] + b1[o]   (bottom half of msg_W1, bias folded)
__global__ void __launch_bounds__(256) kernel_B(
    const float* __restrict__ h, const float* __restrict__ W1,
    const float* __restrict__ b1, float* __restrict__ B)
{
    __shared__ float sw[640 + 32];
    for (int i = threadIdx.x; i < 640; i += 256) sw[i] = W1[640 + i];
    if (threadIdx.x < 32) sw[640 + threadIdx.x] = b1[threadIdx.x];
    __syncthreads();
    int e = blockIdx.x * 256 + threadIdx.x;
    float hv[NF];
    const float4* hp = reinterpret_cast<const float4*>(h + (size_t)e * NF);
    #pragma unroll
    for (int i = 0; i < 5; i++) {
        float4 v = hp[i];
        hv[4*i] = v.x; hv[4*i+1] = v.y; hv[4*i+2] = v.z; hv[4*i+3] = v.w;
    }
    float acc[32];
    #pragma unroll
    for (int o = 0; o < 32; o++) acc[o] = sw[640 + o];
    #pragma unroll
    for (int f = 0; f < NF; f++) {
        float hf = hv[f];
        #pragma unroll
        for (int o = 0; o < 32; o++) acc[o] += hf * sw[f*32 + o];
    }
    float4* Bp = reinterpret_cast<float4*>(B + (size_t)e * 32);
    #pragma unroll
    for (int i = 0; i < 8; i++) {
        float4 v; v.x = acc[4*i]; v.y = acc[4*i+1]; v.z = acc[4*i+2]; v.w = acc[4*i+3];
        Bp[i] = v;
    }
}

// One step: A on the fly, gather 16 contiguous B rows, selu-sum, @W2, GRU.
__global__ void __launch_bounds__(256) kernel_step(
    const float* __restrict__ h_in, float* __restrict__ h_out,
    const float* __restrict__ B, const int* __restrict__ dst,
    const float* __restrict__ W1, const float* __restrict__ W2, const float* __restrict__ b2,
    const float* __restrict__ Wih, const float* __restrict__ Whh,
    const float* __restrict__ bih, const float* __restrict__ bhh)
{
    __shared__ float sW1[640];   // top 20 rows of msg_W1
    __shared__ float sW2[640];   // (32,20)
    __shared__ float sb2[20];
    __shared__ float sWih[1200]; // (60,20)
    __shared__ float sWhh[1200];
    __shared__ float sbih[60];
    __shared__ float sbhh[60];
    for (int i = threadIdx.x; i < 640; i += 256) { sW1[i] = W1[i]; sW2[i] = W2[i]; }
    for (int i = threadIdx.x; i < 1200; i += 256) { sWih[i] = Wih[i]; sWhh[i] = Whh[i]; }
    if (threadIdx.x < 20) sb2[threadIdx.x] = b2[threadIdx.x];
    else if (threadIdx.x >= 64 && threadIdx.x < 124) sbih[threadIdx.x - 64] = bih[threadIdx.x - 64];
    else if (threadIdx.x >= 128 && threadIdx.x < 188) sbhh[threadIdx.x - 128] = bhh[threadIdx.x - 128];
    __syncthreads();

    int e = blockIdx.x * 256 + threadIdx.x;
    float hv[NF];
    const float4* hp = reinterpret_cast<const float4*>(h_in + (size_t)e * NF);
    #pragma unroll
    for (int i = 0; i < 5; i++) {
        float4 v = hp[i];
        hv[4*i] = v.x; hv[4*i+1] = v.y; hv[4*i+2] = v.z; hv[4*i+3] = v.w;
    }
    // A = h_e @ W1_top (bias lives in B)
    float A[32];
    #pragma unroll
    for (int o = 0; o < 32; o++) A[o] = 0.f;
    #pragma unroll
    for (int f = 0; f < NF; f++) {
        float hf = hv[f];
        #pragma unroll
        for (int o = 0; o < 32; o++) A[o] += hf * sW1[f*32 + o];
    }
    int d = dst[e];
    const float4* Bp = reinterpret_cast<const float4*>(B + (size_t)d * 16 * 32);
    float S[32];
    #pragma unroll
    for (int o = 0; o < 32; o++) S[o] = 0.f;
    // consume each float4 of B immediately — keeps live set small (no bj[32])
    #pragma unroll 2
    for (int k = 0; k < 16; k++) {
        const float4* p = Bp + k * 8;
        #pragma unroll
        for (int i = 0; i < 8; i++) {
            float4 v = p[i];
            S[4*i+0] += selu_f(A[4*i+0] + v.x);
            S[4*i+1] += selu_f(A[4*i+1] + v.y);
            S[4*i+2] += selu_f(A[4*i+2] + v.z);
            S[4*i+3] += selu_f(A[4*i+3] + v.w);
        }
    }
    // agg = S @ W2 + 16*b2
    float agg[NF];
    #pragma unroll
    for (int f = 0; f < NF; f++) agg[f] = 16.f * sb2[f];
    #pragma unroll
    for (int o = 0; o < 32; o++) {
        float s = S[o];
        #pragma unroll
        for (int f = 0; f < NF; f++) agg[f] += s * sW2[o*NF + f];
    }
    // GRU
    float hnew[NF];
    #pragma unroll
    for (int c = 0; c < NF; c++) {
        float ir = sbih[c],        hr = sbhh[c];
        float iz = sbih[20 + c],   hz = sbhh[20 + c];
        float in_ = sbih[40 + c],  hn = sbhh[40 + c];
        #pragma unroll
        for (int f = 0; f < NF; f++) {
            float a = agg[f], hh = hv[f];
            ir  += a  * sWih[c*NF + f];
            iz  += a  * sWih[(20 + c)*NF + f];
            in_ += a  * sWih[(40 + c)*NF + f];
            hr  += hh * sWhh[c*NF + f];
            hz  += hh * sWhh[(20 + c)*NF + f];
            hn  += hh * sWhh[(40 + c)*NF + f];
        }
        float r = 1.f / (1.f + __expf(-(ir + hr)));
        float z = 1.f / (1.f + __expf(-(iz + hz)));
        float xn = in_ + r * hn;
        xn = fminf(fmaxf(xn, -20.f), 20.f);
        float t = __expf(2.f * xn);
        float n = (t - 1.f) / (t + 1.f);
        hnew[c] = (1.f - z) * n + z * hv[c];
    }
    float4* op = reinterpret_cast<float4*>(h_out + (size_t)e * NF);
    #pragma unroll
    for (int i = 0; i < 5; i++) {
        float4 v; v.x = hnew[4*i]; v.y = hnew[4*i+1]; v.z = hnew[4*i+2]; v.w = hnew[4*i+3];
        op[i] = v;
    }
}

// Readout: chunk the 64-wide hidden layer (4×16) to bound the live register
// set — previous version spilled (VGPR=256, 10 KB scratch traffic/thread).
__global__ void __launch_bounds__(256) kernel_readout(
    const float* __restrict__ h,
    const float* __restrict__ W1, const float* __restrict__ b1,
    const float* __restrict__ W2, const float* __restrict__ b2,
    const float* __restrict__ W3, const float* __restrict__ b3,
    float* __restrict__ out)
{
    __shared__ float sW1[1280]; // (20,64)
    __shared__ float sb1[64];
    __shared__ float sW2[2048]; // (64,32)
    __shared__ float sb2[32];
    __shared__ float sW3[32];
    __shared__ float sb3;
    for (int i = threadIdx.x; i < 1280; i += 256) sW1[i] = W1[i];
    for (int i = threadIdx.x; i < 2048; i += 256) sW2[i] = W2[i];
    if (threadIdx.x < 64) sb1[threadIdx.x] = b1[threadIdx.x];
    else if (threadIdx.x >= 64 && threadIdx.x < 96) sb2[threadIdx.x - 64] = b2[threadIdx.x - 64];
    else if (threadIdx.x >= 96 && threadIdx.x < 128) sW3[threadIdx.x - 96] = W3[threadIdx.x - 96];
    if (threadIdx.x == 128) sb3 = b3[0];
    __syncthreads();

    int e = blockIdx.x * 256 + threadIdx.x;
    float hv[NF];
    const float4* hp = reinterpret_cast<const float4*>(h + (size_t)e * NF);
    #pragma unroll
    for (int i = 0; i < 5; i++) {
        float4 v = hp[i];
        hv[4*i] = v.x; hv[4*i+1] = v.y; hv[4*i+2] = v.z; hv[4*i+3] = v.w;
    }
    float x2[32];
    #pragma unroll
    for (int o = 0; o < 32; o++) x2[o] = sb2[o];
    // hidden layer in 4 chunks of 16, consumed immediately into x2
    #pragma unroll
    for (int c = 0; c < 4; c++) {
        float x1c[16];
        #pragma unroll
        for (int o = 0; o < 16; o++) x1c[o] = sb1[c*16 + o];
        #pragma unroll
        for (int f = 0; f < NF; f++) {
            float hf = hv[f];
            #pragma unroll
            for (int o = 0; o < 16; o++) x1c[o] += hf * sW1[f*64 + c*16 + o];
        }
        #pragma unroll
        for (int o = 0; o < 16; o++) x1c[o] = selu_f(x1c[o]);
        #pragma unroll
        for (int o = 0; o < 16; o++) {
            float xi = x1c[o];
            int o1 = c*16 + o;
            #pragma unroll
            for (int j = 0; j < 32; j++) x2[j] += xi * sW2[o1*32 + j];
        }
    }
    float acc = sb3;
    #pragma unroll
    for (int o = 0; o < 32; o++) acc += selu_f(x2[o]) * sW3[o];
    float sp = fmaxf(acc, 0.f) + log1pf(__expf(-fabsf(acc)));
    float w = sp + 0.1f;
    w = fminf(fmaxf(w, 0.1f), 10.f);
    out[e] = w;
}

extern "C" void kernel_launch(void* const* d_in, const int* in_sizes, int n_in,
                              void* d_out, int out_size, void* d_ws, size_t ws_size,
                              hipStream_t stream) {
    const float* edge_attr = (const float*)d_in[0];
    const float* msg_W1   = (const float*)d_in[1];
    const float* msg_b1   = (const float*)d_in[2];
    const float* msg_W2   = (const float*)d_in[3];
    const float* msg_b2   = (const float*)d_in[4];
    const float* gru_Wih  = (const float*)d_in[5];
    const float* gru_Whh  = (const float*)d_in[6];
    const float* gru_bih  = (const float*)d_in[7];
    const float* gru_bhh  = (const float*)d_in[8];
    const float* ro_W1    = (const float*)d_in[9];
    const float* ro_b1    = (const float*)d_in[10];
    const float* ro_W2    = (const float*)d_in[11];
    const float* ro_b2    = (const float*)d_in[12];
    const float* ro_W3    = (const float*)d_in[13];
    const float* ro_b3    = (const float*)d_in[14];
    const int* edge_index = (const int*)d_in[15];
    const int* dst = edge_index + E_EDGES;   // row 1 of (2,E)

    float* h_ws = (float*)d_ws;                       // E*20 floats
    float* Bt   = h_ws + (size_t)E_EDGES * NF;        // E*32 floats

    dim3 grid(E_EDGES / 256), block(256);
    const float* hin = edge_attr;
    for (int s = 0; s < 4; s++) {
        kernel_B<<<grid, block, 0, stream>>>(hin, msg_W1, msg_b1, Bt);
        kernel_step<<<grid, block, 0, stream>>>(hin, h_ws, Bt, dst,
            msg_W1, msg_W2, msg_b2, gru_Wih, gru_Whh, gru_bih, gru_bhh);
        hin = h_ws;
    }
    kernel_readout<<<grid, block, 0, stream>>>(h_ws, ro_W1, ro_b1, ro_W2, ro_b2,
                                               ro_W3, ro_b3, (float*)d_out);
}

// Round 3
// 899.610 us; speedup vs baseline: 5.0115x; 5.0115x over previous
//
#include <hip/hip_runtime.h>

#define E_EDGES 320000
#define NF 20

__device__ __forceinline__ float selu_f(float x) {
    const float scale = 1.0507009873554805f;
    const float alpha = 1.6732632423543772f;
    return x > 0.f ? scale * x : scale * alpha * (__expf(x) - 1.f);
}
__device__ __forceinline__ float sigmoid_f(float x) {
    return 1.f / (1.f + __expf(-x));
}
__device__ __forceinline__ float4 f4z() { return make_float4(0.f, 0.f, 0.f, 0.f); }
__device__ __forceinline__ float4 f4fma(float a, float4 b, float4 c) {
    c.x = fmaf(a, b.x, c.x); c.y = fmaf(a, b.y, c.y);
    c.z = fmaf(a, b.z, c.z); c.w = fmaf(a, b.w, c.w); return c;
}
__device__ __forceinline__ float4 f4add(float4 a, float4 b) {
    return make_float4(a.x + b.x, a.y + b.y, a.z + b.z, a.w + b.w);
}
__device__ __forceinline__ float4 f4scale(float s, float4 a) {
    return make_float4(s * a.x, s * a.y, s * a.z, s * a.w);
}
__device__ __forceinline__ float4 selu4(float4 x) {
    x.x = selu_f(x.x); x.y = selu_f(x.y); x.z = selu_f(x.z); x.w = selu_f(x.w); return x;
}
__device__ __forceinline__ float dot20(float4 a0, float4 a1, float4 a2, float4 a3, float4 a4,
                                       const float4* __restrict__ w) {
    float4 w0 = w[0], w1 = w[1], w2 = w[2], w3 = w[3], w4 = w[4];
    float r = a0.x * w0.x;
    r = fmaf(a0.y, w0.y, r); r = fmaf(a0.z, w0.z, r); r = fmaf(a0.w, w0.w, r);
    r = fmaf(a1.x, w1.x, r); r = fmaf(a1.y, w1.y, r); r = fmaf(a1.z, w1.z, r); r = fmaf(a1.w, w1.w, r);
    r = fmaf(a2.x, w2.x, r); r = fmaf(a2.y, w2.y, r); r = fmaf(a2.z, w2.z, r); r = fmaf(a2.w, w2.w, r);
    r = fmaf(a3.x, w3.x, r); r = fmaf(a3.y, w3.y, r); r = fmaf(a3.z, w3.z, r); r = fmaf(a3.w, w3.w, r);
    r = fmaf(a4.x, w4.x, r); r = fmaf(a4.y, w4.y, r); r = fmaf(a4.z, w4.z, r); r = fmaf(a4.w, w4.w, r);
    return r;
}
__device__ __forceinline__ float dot4(float4 a, float4 b) {
    float r = a.x * b.x; r = fmaf(a.y, b.y, r); r = fmaf(a.z, b.z, r); r = fmaf(a.w, b.w, r);
    return r;
}

// iterate f=0..19 with hf drawn from named float4s v0..v4 — NO private array
#define FOR20(X) \
  X(0, v0.x) X(1, v0.y) X(2, v0.z) X(3, v0.w) \
  X(4, v1.x) X(5, v1.y) X(6, v1.z) X(7, v1.w) \
  X(8, v2.x) X(9, v2.y) X(10, v2.z) X(11, v2.w) \
  X(12, v3.x) X(13, v3.y) X(14, v3.z) X(15, v3.w) \
  X(16, v4.x) X(17, v4.y) X(18, v4.z) X(19, v4.w)

#define FOR32S(X) \
  X(0, s0.x) X(1, s0.y) X(2, s0.z) X(3, s0.w) \
  X(4, s1.x) X(5, s1.y) X(6, s1.z) X(7, s1.w) \
  X(8, s2.x) X(9, s2.y) X(10, s2.z) X(11, s2.w) \
  X(12, s3.x) X(13, s3.y) X(14, s3.z) X(15, s3.w) \
  X(16, s4.x) X(17, s4.y) X(18, s4.z) X(19, s4.w) \
  X(20, s5.x) X(21, s5.y) X(22, s5.z) X(23, s5.w) \
  X(24, s6.x) X(25, s6.y) X(26, s6.z) X(27, s6.w) \
  X(28, s7.x) X(29, s7.y) X(30, s7.z) X(31, s7.w)

// B[e][o] = sum_f h[e][f] * W1[20+f][o] + b1[o]
__global__ void __launch_bounds__(256) kernel_B(
    const float* __restrict__ h, const float* __restrict__ W1,
    const float* __restrict__ b1, float* __restrict__ B)
{
    __shared__ __align__(16) float sw[640];
    __shared__ __align__(16) float sbias[32];
    for (int i = threadIdx.x; i < 640; i += 256) sw[i] = W1[640 + i];
    if (threadIdx.x < 32) sbias[threadIdx.x] = b1[threadIdx.x];
    __syncthreads();
    int e = blockIdx.x * 256 + threadIdx.x;
    const float4* hp = reinterpret_cast<const float4*>(h + (size_t)e * NF);
    float4 v0 = hp[0], v1 = hp[1], v2 = hp[2], v3 = hp[3], v4 = hp[4];
    const float4* bi = reinterpret_cast<const float4*>(sbias);
    float4 c0 = bi[0], c1 = bi[1], c2 = bi[2], c3 = bi[3],
           c4 = bi[4], c5 = bi[5], c6 = bi[6], c7 = bi[7];
    #define BSTEP(f, hf) { float t_ = (hf); const float4* w_ = (const float4*)&sw[(f)*32]; \
        c0 = f4fma(t_, w_[0], c0); c1 = f4fma(t_, w_[1], c1); \
        c2 = f4fma(t_, w_[2], c2); c3 = f4fma(t_, w_[3], c3); \
        c4 = f4fma(t_, w_[4], c4); c5 = f4fma(t_, w_[5], c5); \
        c6 = f4fma(t_, w_[6], c6); c7 = f4fma(t_, w_[7], c7); }
    FOR20(BSTEP)
    #undef BSTEP
    float4* Bp = reinterpret_cast<float4*>(B + (size_t)e * 32);
    Bp[0] = c0; Bp[1] = c1; Bp[2] = c2; Bp[3] = c3;
    Bp[4] = c4; Bp[5] = c5; Bp[6] = c6; Bp[7] = c7;
}

__global__ void __launch_bounds__(256) kernel_step(
    const float* __restrict__ h_in, float* __restrict__ h_out,
    const float* __restrict__ B, const int* __restrict__ dst,
    const float* __restrict__ W1, const float* __restrict__ W2, const float* __restrict__ b2,
    const float* __restrict__ Wih, const float* __restrict__ Whh,
    const float* __restrict__ bih, const float* __restrict__ bhh)
{
    __shared__ __align__(16) float sW1[640];   // top 20 rows of msg_W1, (20,32)
    __shared__ __align__(16) float sW2[640];   // (32,20)
    __shared__ __align__(16) float sb2v[20];
    __shared__ __align__(16) float sWih[1200]; // (60,20)
    __shared__ __align__(16) float sWhh[1200];
    __shared__ float sbih[60];
    __shared__ float sbhh[60];
    for (int i = threadIdx.x; i < 640; i += 256) { sW1[i] = W1[i]; sW2[i] = W2[i]; }
    for (int i = threadIdx.x; i < 1200; i += 256) { sWih[i] = Wih[i]; sWhh[i] = Whh[i]; }
    if (threadIdx.x < 20) sb2v[threadIdx.x] = b2[threadIdx.x];
    else if (threadIdx.x >= 64 && threadIdx.x < 124) sbih[threadIdx.x - 64] = bih[threadIdx.x - 64];
    else if (threadIdx.x >= 128 && threadIdx.x < 188) sbhh[threadIdx.x - 128] = bhh[threadIdx.x - 128];
    __syncthreads();

    int e = blockIdx.x * 256 + threadIdx.x;
    const float4* hp = reinterpret_cast<const float4*>(h_in + (size_t)e * NF);
    float4 v0 = hp[0], v1 = hp[1], v2 = hp[2], v3 = hp[3], v4 = hp[4];

    // A = h_e @ W1_top
    float4 a0 = f4z(), a1 = f4z(), a2 = f4z(), a3 = f4z(),
           a4 = f4z(), a5 = f4z(), a6 = f4z(), a7 = f4z();
    #define ASTEP(f, hf) { float t_ = (hf); const float4* w_ = (const float4*)&sW1[(f)*32]; \
        a0 = f4fma(t_, w_[0], a0); a1 = f4fma(t_, w_[1], a1); \
        a2 = f4fma(t_, w_[2], a2); a3 = f4fma(t_, w_[3], a3); \
        a4 = f4fma(t_, w_[4], a4); a5 = f4fma(t_, w_[5], a5); \
        a6 = f4fma(t_, w_[6], a6); a7 = f4fma(t_, w_[7], a7); }
    FOR20(ASTEP)
    #undef ASTEP

    int d = dst[e];
    const float4* Bp = reinterpret_cast<const float4*>(B + (size_t)d * 16 * 32);
    float4 s0 = f4z(), s1 = f4z(), s2 = f4z(), s3 = f4z(),
           s4 = f4z(), s5 = f4z(), s6 = f4z(), s7 = f4z();
    for (int k = 0; k < 16; k++) {
        const float4* p = Bp + k * 8;
        float4 t0 = p[0], t1 = p[1], t2 = p[2], t3 = p[3],
               t4 = p[4], t5 = p[5], t6 = p[6], t7 = p[7];
        s0 = f4add(s0, selu4(f4add(a0, t0)));
        s1 = f4add(s1, selu4(f4add(a1, t1)));
        s2 = f4add(s2, selu4(f4add(a2, t2)));
        s3 = f4add(s3, selu4(f4add(a3, t3)));
        s4 = f4add(s4, selu4(f4add(a4, t4)));
        s5 = f4add(s5, selu4(f4add(a5, t5)));
        s6 = f4add(s6, selu4(f4add(a6, t6)));
        s7 = f4add(s7, selu4(f4add(a7, t7)));
    }

    // agg = S @ W2 + 16*b2
    const float4* b2p = reinterpret_cast<const float4*>(sb2v);
    float4 g0 = f4scale(16.f, b2p[0]), g1 = f4scale(16.f, b2p[1]),
           g2 = f4scale(16.f, b2p[2]), g3 = f4scale(16.f, b2p[3]),
           g4 = f4scale(16.f, b2p[4]);
    #define AGGS(o, sc) { float t_ = (sc); const float4* w_ = (const float4*)&sW2[(o)*20]; \
        g0 = f4fma(t_, w_[0], g0); g1 = f4fma(t_, w_[1], g1); \
        g2 = f4fma(t_, w_[2], g2); g3 = f4fma(t_, w_[3], g3); \
        g4 = f4fma(t_, w_[4], g4); }
    FOR32S(AGGS)
    #undef AGGS

    // GRU, one channel at a time — only LDS/global indexed dynamically
    for (int c = 0; c < 20; c++) {
        float ir = sbih[c]      + dot20(g0, g1, g2, g3, g4, (const float4*)&sWih[c * 20]);
        float iz = sbih[20 + c] + dot20(g0, g1, g2, g3, g4, (const float4*)&sWih[(20 + c) * 20]);
        float in_ = sbih[40 + c] + dot20(g0, g1, g2, g3, g4, (const float4*)&sWih[(40 + c) * 20]);
        float hr = sbhh[c]      + dot20(v0, v1, v2, v3, v4, (const float4*)&sWhh[c * 20]);
        float hz = sbhh[20 + c] + dot20(v0, v1, v2, v3, v4, (const float4*)&sWhh[(20 + c) * 20]);
        float hn = sbhh[40 + c] + dot20(v0, v1, v2, v3, v4, (const float4*)&sWhh[(40 + c) * 20]);
        float r = sigmoid_f(ir + hr);
        float z = sigmoid_f(iz + hz);
        float xn = in_ + r * hn;
        xn = fminf(fmaxf(xn, -20.f), 20.f);
        float t = __expf(2.f * xn);
        float n = (t - 1.f) / (t + 1.f);
        float hc = h_in[(size_t)e * NF + c];   // L1-hot re-read (avoids private array)
        h_out[(size_t)e * NF + c] = (1.f - z) * n + z * hc;
    }
}

__global__ void __launch_bounds__(256) kernel_readout(
    const float* __restrict__ h,
    const float* __restrict__ W1, const float* __restrict__ b1,
    const float* __restrict__ W2, const float* __restrict__ b2,
    const float* __restrict__ W3, const float* __restrict__ b3,
    float* __restrict__ out)
{
    __shared__ __align__(16) float sW1t[1280]; // transposed: (64,20)
    __shared__ float sb1[64];
    __shared__ __align__(16) float sW2[2048];  // (64,32)
    __shared__ __align__(16) float sb2v[32];
    __shared__ __align__(16) float sW3[32];
    __shared__ float sb3;
    for (int i = threadIdx.x; i < 1280; i += 256) {
        int f = i >> 6, o = i & 63;
        sW1t[o * 20 + f] = W1[i];
    }
    for (int i = threadIdx.x; i < 2048; i += 256) sW2[i] = W2[i];
    if (threadIdx.x < 64) sb1[threadIdx.x] = b1[threadIdx.x];
    else if (threadIdx.x >= 64 && threadIdx.x < 96) sb2v[threadIdx.x - 64] = b2[threadIdx.x - 64];
    else if (threadIdx.x >= 96 && threadIdx.x < 128) sW3[threadIdx.x - 96] = W3[threadIdx.x - 96];
    if (threadIdx.x == 128) sb3 = b3[0];
    __syncthreads();

    int e = blockIdx.x * 256 + threadIdx.x;
    const float4* hp = reinterpret_cast<const float4*>(h + (size_t)e * NF);
    float4 v0 = hp[0], v1 = hp[1], v2 = hp[2], v3 = hp[3], v4 = hp[4];

    const float4* b2p = reinterpret_cast<const float4*>(sb2v);
    float4 x20 = b2p[0], x21 = b2p[1], x22 = b2p[2], x23 = b2p[3],
           x24 = b2p[4], x25 = b2p[5], x26 = b2p[6], x27 = b2p[7];
    for (int o = 0; o < 64; o++) {
        float x1 = sb1[o] + dot20(v0, v1, v2, v3, v4, (const float4*)&sW1t[o * 20]);
        x1 = selu_f(x1);
        const float4* w = (const float4*)&sW2[o * 32];
        x20 = f4fma(x1, w[0], x20); x21 = f4fma(x1, w[1], x21);
        x22 = f4fma(x1, w[2], x22); x23 = f4fma(x1, w[3], x23);
        x24 = f4fma(x1, w[4], x24); x25 = f4fma(x1, w[5], x25);
        x26 = f4fma(x1, w[6], x26); x27 = f4fma(x1, w[7], x27);
    }
    const float4* w3p = reinterpret_cast<const float4*>(sW3);
    float acc = sb3;
    acc += dot4(selu4(x20), w3p[0]); acc += dot4(selu4(x21), w3p[1]);
    acc += dot4(selu4(x22), w3p[2]); acc += dot4(selu4(x23), w3p[3]);
    acc += dot4(selu4(x24), w3p[4]); acc += dot4(selu4(x25), w3p[5]);
    acc += dot4(selu4(x26), w3p[6]); acc += dot4(selu4(x27), w3p[7]);
    float sp = fmaxf(acc, 0.f) + log1pf(__expf(-fabsf(acc)));
    float w = sp + 0.1f;
    w = fminf(fmaxf(w, 0.1f), 10.f);
    out[e] = w;
}

extern "C" void kernel_launch(void* const* d_in, const int* in_sizes, int n_in,
                              void* d_out, int out_size, void* d_ws, size_t ws_size,
                              hipStream_t stream) {
    const float* edge_attr = (const float*)d_in[0];
    const float* msg_W1   = (const float*)d_in[1];
    const float* msg_b1   = (const float*)d_in[2];
    const float* msg_W2   = (const float*)d_in[3];
    const float* msg_b2   = (const float*)d_in[4];
    const float* gru_Wih  = (const float*)d_in[5];
    const float* gru_Whh  = (const float*)d_in[6];
    const float* gru_bih  = (const float*)d_in[7];
    const float* gru_bhh  = (const float*)d_in[8];
    const float* ro_W1    = (const float*)d_in[9];
    const float* ro_b1    = (const float*)d_in[10];
    const float* ro_W2    = (const float*)d_in[11];
    const float* ro_b2    = (const float*)d_in[12];
    const float* ro_W3    = (const float*)d_in[13];
    const float* ro_b3    = (const float*)d_in[14];
    const int* edge_index = (const int*)d_in[15];
    const int* dst = edge_index + E_EDGES;   // row 1 of (2,E)

    float* h_ws = (float*)d_ws;                       // E*20 floats
    float* Bt   = h_ws + (size_t)E_EDGES * NF;        // E*32 floats

    dim3 grid(E_EDGES / 256), block(256);
    const float* hin = edge_attr;
    for (int s = 0; s < 4; s++) {
        kernel_B<<<grid, block, 0, stream>>>(hin, msg_W1, msg_b1, Bt);
        kernel_step<<<grid, block, 0, stream>>>(hin, h_ws, Bt, dst,
            msg_W1, msg_W2, msg_b2, gru_Wih, gru_Whh, gru_bih, gru_bhh);
        hin = h_ws;
    }
    kernel_readout<<<grid, block, 0, stream>>>(h_ws, ro_W1, ro_b1, ro_W2, ro_b2,
                                               ro_W3, ro_b3, (float*)d_out);
}

// Round 4
// 754.954 us; speedup vs baseline: 5.9718x; 1.1916x over previous
//
#include <hip/hip_runtime.h>

#define E_EDGES 320000
#define NF 20

__device__ __forceinline__ float selu_f(float x) {
    const float scale = 1.0507009873554805f;
    const float alpha = 1.6732632423543772f;
    return x > 0.f ? scale * x : scale * alpha * (__expf(x) - 1.f);
}
__device__ __forceinline__ float sigmoid_f(float x) {
    return 1.f / (1.f + __expf(-x));
}
__device__ __forceinline__ float4 f4z() { return make_float4(0.f, 0.f, 0.f, 0.f); }
__device__ __forceinline__ float4 f4fma(float a, float4 b, float4 c) {
    c.x = fmaf(a, b.x, c.x); c.y = fmaf(a, b.y, c.y);
    c.z = fmaf(a, b.z, c.z); c.w = fmaf(a, b.w, c.w); return c;
}
__device__ __forceinline__ float4 f4add(float4 a, float4 b) {
    return make_float4(a.x + b.x, a.y + b.y, a.z + b.z, a.w + b.w);
}
__device__ __forceinline__ float4 selu4(float4 x) {
    x.x = selu_f(x.x); x.y = selu_f(x.y); x.z = selu_f(x.z); x.w = selu_f(x.w); return x;
}
__device__ __forceinline__ float dot20(float4 a0, float4 a1, float4 a2, float4 a3, float4 a4,
                                       const float4* __restrict__ w) {
    float4 w0 = w[0], w1 = w[1], w2 = w[2], w3 = w[3], w4 = w[4];
    float r = a0.x * w0.x;
    r = fmaf(a0.y, w0.y, r); r = fmaf(a0.z, w0.z, r); r = fmaf(a0.w, w0.w, r);
    r = fmaf(a1.x, w1.x, r); r = fmaf(a1.y, w1.y, r); r = fmaf(a1.z, w1.z, r); r = fmaf(a1.w, w1.w, r);
    r = fmaf(a2.x, w2.x, r); r = fmaf(a2.y, w2.y, r); r = fmaf(a2.z, w2.z, r); r = fmaf(a2.w, w2.w, r);
    r = fmaf(a3.x, w3.x, r); r = fmaf(a3.y, w3.y, r); r = fmaf(a3.z, w3.z, r); r = fmaf(a3.w, w3.w, r);
    r = fmaf(a4.x, w4.x, r); r = fmaf(a4.y, w4.y, r); r = fmaf(a4.z, w4.z, r); r = fmaf(a4.w, w4.w, r);
    return r;
}
__device__ __forceinline__ float dot4(float4 a, float4 b) {
    float r = a.x * b.x; r = fmaf(a.y, b.y, r); r = fmaf(a.z, b.z, r); r = fmaf(a.w, b.w, r);
    return r;
}

#define FOR20(X) \
  X(0, v0.x) X(1, v0.y) X(2, v0.z) X(3, v0.w) \
  X(4, v1.x) X(5, v1.y) X(6, v1.z) X(7, v1.w) \
  X(8, v2.x) X(9, v2.y) X(10, v2.z) X(11, v2.w) \
  X(12, v3.x) X(13, v3.y) X(14, v3.z) X(15, v3.w) \
  X(16, v4.x) X(17, v4.y) X(18, v4.z) X(19, v4.w)

#define FOR8S(X) \
  X(0, s0.x) X(1, s0.y) X(2, s0.z) X(3, s0.w) \
  X(4, s1.x) X(5, s1.y) X(6, s1.z) X(7, s1.w)

// B[e][o] = sum_f h[e][f] * W1[20+f][o] + b1[o]
__global__ void __launch_bounds__(256) kernel_B(
    const float* __restrict__ h, const float* __restrict__ W1,
    const float* __restrict__ b1, float* __restrict__ B)
{
    __shared__ __align__(16) float sw[640];
    __shared__ __align__(16) float sbias[32];
    for (int i = threadIdx.x; i < 640; i += 256) sw[i] = W1[640 + i];
    if (threadIdx.x < 32) sbias[threadIdx.x] = b1[threadIdx.x];
    __syncthreads();
    int e = blockIdx.x * 256 + threadIdx.x;
    const float4* hp = reinterpret_cast<const float4*>(h + (size_t)e * NF);
    float4 v0 = hp[0], v1 = hp[1], v2 = hp[2], v3 = hp[3], v4 = hp[4];
    const float4* bi = reinterpret_cast<const float4*>(sbias);
    float4 c0 = bi[0], c1 = bi[1], c2 = bi[2], c3 = bi[3],
           c4 = bi[4], c5 = bi[5], c6 = bi[6], c7 = bi[7];
    #define BSTEP(f, hf) { float t_ = (hf); const float4* w_ = (const float4*)&sw[(f)*32]; \
        c0 = f4fma(t_, w_[0], c0); c1 = f4fma(t_, w_[1], c1); \
        c2 = f4fma(t_, w_[2], c2); c3 = f4fma(t_, w_[3], c3); \
        c4 = f4fma(t_, w_[4], c4); c5 = f4fma(t_, w_[5], c5); \
        c6 = f4fma(t_, w_[6], c6); c7 = f4fma(t_, w_[7], c7); }
    FOR20(BSTEP)
    #undef BSTEP
    float4* Bp = reinterpret_cast<float4*>(B + (size_t)e * 32);
    Bp[0] = c0; Bp[1] = c1; Bp[2] = c2; Bp[3] = c3;
    Bp[4] = c4; Bp[5] = c5; Bp[6] = c6; Bp[7] = c7;
}

// One step, 4 lanes per edge (quad). Lane q owns message channels q*8..q*8+7
// and GRU channels q*5..q*5+4. agg reduced across the quad via shfl_xor.
__global__ void __launch_bounds__(256) kernel_step(
    const float* __restrict__ h_in, float* __restrict__ h_out,
    const float* __restrict__ B, const int* __restrict__ dst,
    const float* __restrict__ W1, const float* __restrict__ W2, const float* __restrict__ b2,
    const float* __restrict__ Wih, const float* __restrict__ Whh,
    const float* __restrict__ bih, const float* __restrict__ bhh)
{
    __shared__ __align__(16) float sW1[640];   // top 20 rows of msg_W1, (20,32)
    __shared__ __align__(16) float sW2[640];   // (32,20)
    __shared__ __align__(16) float sb2v[20];
    __shared__ __align__(16) float sWih[1200]; // (60,20)
    __shared__ __align__(16) float sWhh[1200];
    __shared__ float sbih[60];
    __shared__ float sbhh[60];
    for (int i = threadIdx.x; i < 640; i += 256) { sW1[i] = W1[i]; sW2[i] = W2[i]; }
    for (int i = threadIdx.x; i < 1200; i += 256) { sWih[i] = Wih[i]; sWhh[i] = Whh[i]; }
    if (threadIdx.x < 20) sb2v[threadIdx.x] = b2[threadIdx.x];
    else if (threadIdx.x >= 64 && threadIdx.x < 124) sbih[threadIdx.x - 64] = bih[threadIdx.x - 64];
    else if (threadIdx.x >= 128 && threadIdx.x < 188) sbhh[threadIdx.x - 128] = bhh[threadIdx.x - 188 + 60];
    __syncthreads();

    int t = blockIdx.x * 256 + threadIdx.x;
    int e = t >> 2;
    int q = t & 3;
    int ob = q * 8;                 // first of this lane's 8 message channels

    int d = dst[e];                 // issue early
    const float4* hp = reinterpret_cast<const float4*>(h_in + (size_t)e * NF);
    float4 v0 = hp[0], v1 = hp[1], v2 = hp[2], v3 = hp[3], v4 = hp[4];

    // A[ob..ob+7] = (h_e @ W1_top)[ob..ob+7]
    float4 a0 = f4z(), a1 = f4z();
    #define ASTEP(f, hf) { float t_ = (hf); const float4* w_ = (const float4*)&sW1[(f)*32 + ob]; \
        a0 = f4fma(t_, w_[0], a0); a1 = f4fma(t_, w_[1], a1); }
    FOR20(ASTEP)
    #undef ASTEP

    // gather 16 rows of B (lane takes its 32B slice of each 128B row)
    const float4* Bp = reinterpret_cast<const float4*>(B + (size_t)d * 16 * 32) + (ob >> 2);
    float4 s0 = f4z(), s1 = f4z();
    #pragma unroll 4
    for (int k = 0; k < 16; k++) {
        float4 t0 = Bp[k * 8 + 0];
        float4 t1 = Bp[k * 8 + 1];
        s0 = f4add(s0, selu4(f4add(a0, t0)));
        s1 = f4add(s1, selu4(f4add(a1, t1)));
    }

    // partial agg over this lane's 8 channels: rows ob..ob+7 of W2 (32,20)
    float4 g0 = f4z(), g1 = f4z(), g2 = f4z(), g3 = f4z(), g4 = f4z();
    #define AGGS(j, sc) { float t_ = (sc); const float4* w_ = (const float4*)&sW2[(ob + (j)) * 20]; \
        g0 = f4fma(t_, w_[0], g0); g1 = f4fma(t_, w_[1], g1); \
        g2 = f4fma(t_, w_[2], g2); g3 = f4fma(t_, w_[3], g3); \
        g4 = f4fma(t_, w_[4], g4); }
    FOR8S(AGGS)
    #undef AGGS

    // quad butterfly: all 4 lanes end with the full 20-float agg
    #define BFLY(m_) \
      g0.x += __shfl_xor(g0.x, m_); g0.y += __shfl_xor(g0.y, m_); g0.z += __shfl_xor(g0.z, m_); g0.w += __shfl_xor(g0.w, m_); \
      g1.x += __shfl_xor(g1.x, m_); g1.y += __shfl_xor(g1.y, m_); g1.z += __shfl_xor(g1.z, m_); g1.w += __shfl_xor(g1.w, m_); \
      g2.x += __shfl_xor(g2.x, m_); g2.y += __shfl_xor(g2.y, m_); g2.z += __shfl_xor(g2.z, m_); g2.w += __shfl_xor(g2.w, m_); \
      g3.x += __shfl_xor(g3.x, m_); g3.y += __shfl_xor(g3.y, m_); g3.z += __shfl_xor(g3.z, m_); g3.w += __shfl_xor(g3.w, m_); \
      g4.x += __shfl_xor(g4.x, m_); g4.y += __shfl_xor(g4.y, m_); g4.z += __shfl_xor(g4.z, m_); g4.w += __shfl_xor(g4.w, m_);
    BFLY(1)
    BFLY(2)
    #undef BFLY

    // add 16*b2 once (after reduction)
    {
        const float4* b2p = reinterpret_cast<const float4*>(sb2v);
        g0 = f4fma(16.f, b2p[0], g0); g1 = f4fma(16.f, b2p[1], g1);
        g2 = f4fma(16.f, b2p[2], g2); g3 = f4fma(16.f, b2p[3], g3);
        g4 = f4fma(16.f, b2p[4], g4);
    }

    // GRU: 5 channels per lane
    for (int i = 0; i < 5; i++) {
        int c = q * 5 + i;
        float ir  = sbih[c]      + dot20(g0, g1, g2, g3, g4, (const float4*)&sWih[c * 20]);
        float iz  = sbih[20 + c] + dot20(g0, g1, g2, g3, g4, (const float4*)&sWih[(20 + c) * 20]);
        float in_ = sbih[40 + c] + dot20(g0, g1, g2, g3, g4, (const float4*)&sWih[(40 + c) * 20]);
        float hr  = sbhh[c]      + dot20(v0, v1, v2, v3, v4, (const float4*)&sWhh[c * 20]);
        float hz  = sbhh[20 + c] + dot20(v0, v1, v2, v3, v4, (const float4*)&sWhh[(20 + c) * 20]);
        float hn  = sbhh[40 + c] + dot20(v0, v1, v2, v3, v4, (const float4*)&sWhh[(40 + c) * 20]);
        float r = sigmoid_f(ir + hr);
        float z = sigmoid_f(iz + hz);
        float xn = in_ + r * hn;
        xn = fminf(fmaxf(xn, -20.f), 20.f);
        float tt = __expf(2.f * xn);
        float n = (tt - 1.f) / (tt + 1.f);
        float hc = h_in[(size_t)e * NF + c];   // L1-hot scalar re-read
        h_out[(size_t)e * NF + c] = (1.f - z) * n + z * hc;
    }
}

__global__ void __launch_bounds__(256) kernel_readout(
    const float* __restrict__ h,
    const float* __restrict__ W1, const float* __restrict__ b1,
    const float* __restrict__ W2, const float* __restrict__ b2,
    const float* __restrict__ W3, const float* __restrict__ b3,
    float* __restrict__ out)
{
    __shared__ __align__(16) float sW1t[1280]; // transposed: (64,20)
    __shared__ float sb1[64];
    __shared__ __align__(16) float sW2[2048];  // (64,32)
    __shared__ __align__(16) float sb2v[32];
    __shared__ __align__(16) float sW3[32];
    __shared__ float sb3;
    for (int i = threadIdx.x; i < 1280; i += 256) {
        int f = i >> 6, o = i & 63;
        sW1t[o * 20 + f] = W1[i];
    }
    for (int i = threadIdx.x; i < 2048; i += 256) sW2[i] = W2[i];
    if (threadIdx.x < 64) sb1[threadIdx.x] = b1[threadIdx.x];
    else if (threadIdx.x >= 64 && threadIdx.x < 96) sb2v[threadIdx.x - 64] = b2[threadIdx.x - 64];
    else if (threadIdx.x >= 96 && threadIdx.x < 128) sW3[threadIdx.x - 96] = W3[threadIdx.x - 96];
    if (threadIdx.x == 128) sb3 = b3[0];
    __syncthreads();

    int e = blockIdx.x * 256 + threadIdx.x;
    const float4* hp = reinterpret_cast<const float4*>(h + (size_t)e * NF);
    float4 v0 = hp[0], v1 = hp[1], v2 = hp[2], v3 = hp[3], v4 = hp[4];

    const float4* b2p = reinterpret_cast<const float4*>(sb2v);
    float4 x20 = b2p[0], x21 = b2p[1], x22 = b2p[2], x23 = b2p[3],
           x24 = b2p[4], x25 = b2p[5], x26 = b2p[6], x27 = b2p[7];
    for (int o = 0; o < 64; o++) {
        float x1 = sb1[o] + dot20(v0, v1, v2, v3, v4, (const float4*)&sW1t[o * 20]);
        x1 = selu_f(x1);
        const float4* w = (const float4*)&sW2[o * 32];
        x20 = f4fma(x1, w[0], x20); x21 = f4fma(x1, w[1], x21);
        x22 = f4fma(x1, w[2], x22); x23 = f4fma(x1, w[3], x23);
        x24 = f4fma(x1, w[4], x24); x25 = f4fma(x1, w[5], x25);
        x26 = f4fma(x1, w[6], x26); x27 = f4fma(x1, w[7], x27);
    }
    const float4* w3p = reinterpret_cast<const float4*>(sW3);
    float acc = sb3;
    acc += dot4(selu4(x20), w3p[0]); acc += dot4(selu4(x21), w3p[1]);
    acc += dot4(selu4(x22), w3p[2]); acc += dot4(selu4(x23), w3p[3]);
    acc += dot4(selu4(x24), w3p[4]); acc += dot4(selu4(x25), w3p[5]);
    acc += dot4(selu4(x26), w3p[6]); acc += dot4(selu4(x27), w3p[7]);
    float sp = fmaxf(acc, 0.f) + log1pf(__expf(-fabsf(acc)));
    float w = sp + 0.1f;
    w = fminf(fmaxf(w, 0.1f), 10.f);
    out[e] = w;
}

extern "C" void kernel_launch(void* const* d_in, const int* in_sizes, int n_in,
                              void* d_out, int out_size, void* d_ws, size_t ws_size,
                              hipStream_t stream) {
    const float* edge_attr = (const float*)d_in[0];
    const float* msg_W1   = (const float*)d_in[1];
    const float* msg_b1   = (const float*)d_in[2];
    const float* msg_W2   = (const float*)d_in[3];
    const float* msg_b2   = (const float*)d_in[4];
    const float* gru_Wih  = (const float*)d_in[5];
    const float* gru_Whh  = (const float*)d_in[6];
    const float* gru_bih  = (const float*)d_in[7];
    const float* gru_bhh  = (const float*)d_in[8];
    const float* ro_W1    = (const float*)d_in[9];
    const float* ro_b1    = (const float*)d_in[10];
    const float* ro_W2    = (const float*)d_in[11];
    const float* ro_b2    = (const float*)d_in[12];
    const float* ro_W3    = (const float*)d_in[13];
    const float* ro_b3    = (const float*)d_in[14];
    const int* edge_index = (const int*)d_in[15];
    const int* dst = edge_index + E_EDGES;   // row 1 of (2,E)

    float* h_ws = (float*)d_ws;                       // E*20 floats
    float* Bt   = h_ws + (size_t)E_EDGES * NF;        // E*32 floats

    dim3 gridB(E_EDGES / 256), block(256);
    dim3 gridS(E_EDGES / 64);          // 4 lanes per edge
    const float* hin = edge_attr;
    for (int s = 0; s < 4; s++) {
        kernel_B<<<gridB, block, 0, stream>>>(hin, msg_W1, msg_b1, Bt);
        kernel_step<<<gridS, block, 0, stream>>>(hin, h_ws, Bt, dst,
            msg_W1, msg_W2, msg_b2, gru_Wih, gru_Whh, gru_bih, gru_bhh);
        hin = h_ws;
    }
    kernel_readout<<<gridB, block, 0, stream>>>(h_ws, ro_W1, ro_b1, ro_W2, ro_b2,
                                                ro_W3, ro_b3, (float*)d_out);
}

// Round 5
// 693.935 us; speedup vs baseline: 6.4969x; 1.0879x over previous
//
#include <hip/hip_runtime.h>

#define E_EDGES 320000
#define NF 20

__device__ __forceinline__ float selu_f(float x) {
    const float scale = 1.0507009873554805f;
    const float alpha = 1.6732632423543772f;
    return x > 0.f ? scale * x : scale * alpha * (__expf(x) - 1.f);
}
__device__ __forceinline__ float sigmoid_f(float x) {
    return 1.f / (1.f + __expf(-x));
}
__device__ __forceinline__ float4 f4z() { return make_float4(0.f, 0.f, 0.f, 0.f); }
__device__ __forceinline__ float4 f4fma(float a, float4 b, float4 c) {
    c.x = fmaf(a, b.x, c.x); c.y = fmaf(a, b.y, c.y);
    c.z = fmaf(a, b.z, c.z); c.w = fmaf(a, b.w, c.w); return c;
}
__device__ __forceinline__ float4 f4add(float4 a, float4 b) {
    return make_float4(a.x + b.x, a.y + b.y, a.z + b.z, a.w + b.w);
}
__device__ __forceinline__ float4 selu4(float4 x) {
    x.x = selu_f(x.x); x.y = selu_f(x.y); x.z = selu_f(x.z); x.w = selu_f(x.w); return x;
}
__device__ __forceinline__ float dot20(float4 a0, float4 a1, float4 a2, float4 a3, float4 a4,
                                       const float4* __restrict__ w) {
    float4 w0 = w[0], w1 = w[1], w2 = w[2], w3 = w[3], w4 = w[4];
    float r = a0.x * w0.x;
    r = fmaf(a0.y, w0.y, r); r = fmaf(a0.z, w0.z, r); r = fmaf(a0.w, w0.w, r);
    r = fmaf(a1.x, w1.x, r); r = fmaf(a1.y, w1.y, r); r = fmaf(a1.z, w1.z, r); r = fmaf(a1.w, w1.w, r);
    r = fmaf(a2.x, w2.x, r); r = fmaf(a2.y, w2.y, r); r = fmaf(a2.z, w2.z, r); r = fmaf(a2.w, w2.w, r);
    r = fmaf(a3.x, w3.x, r); r = fmaf(a3.y, w3.y, r); r = fmaf(a3.z, w3.z, r); r = fmaf(a3.w, w3.w, r);
    r = fmaf(a4.x, w4.x, r); r = fmaf(a4.y, w4.y, r); r = fmaf(a4.z, w4.z, r); r = fmaf(a4.w, w4.w, r);
    return r;
}
// one LDS row read serves BOTH edges — this is the DS-bandwidth saver
__device__ __forceinline__ void dot20_dual(const float4* __restrict__ w,
    float4 a0, float4 a1, float4 a2, float4 a3, float4 a4,
    float4 b0, float4 b1, float4 b2, float4 b3, float4 b4,
    float& r0, float& r1)
{
    float4 w0 = w[0], w1 = w[1], w2 = w[2], w3 = w[3], w4 = w[4];
    float r = a0.x * w0.x;
    r = fmaf(a0.y, w0.y, r); r = fmaf(a0.z, w0.z, r); r = fmaf(a0.w, w0.w, r);
    r = fmaf(a1.x, w1.x, r); r = fmaf(a1.y, w1.y, r); r = fmaf(a1.z, w1.z, r); r = fmaf(a1.w, w1.w, r);
    r = fmaf(a2.x, w2.x, r); r = fmaf(a2.y, w2.y, r); r = fmaf(a2.z, w2.z, r); r = fmaf(a2.w, w2.w, r);
    r = fmaf(a3.x, w3.x, r); r = fmaf(a3.y, w3.y, r); r = fmaf(a3.z, w3.z, r); r = fmaf(a3.w, w3.w, r);
    r = fmaf(a4.x, w4.x, r); r = fmaf(a4.y, w4.y, r); r = fmaf(a4.z, w4.z, r); r = fmaf(a4.w, w4.w, r);
    r0 = r;
    float s = b0.x * w0.x;
    s = fmaf(b0.y, w0.y, s); s = fmaf(b0.z, w0.z, s); s = fmaf(b0.w, w0.w, s);
    s = fmaf(b1.x, w1.x, s); s = fmaf(b1.y, w1.y, s); s = fmaf(b1.z, w1.z, s); s = fmaf(b1.w, w1.w, s);
    s = fmaf(b2.x, w2.x, s); s = fmaf(b2.y, w2.y, s); s = fmaf(b2.z, w2.z, s); s = fmaf(b2.w, w2.w, s);
    s = fmaf(b3.x, w3.x, s); s = fmaf(b3.y, w3.y, s); s = fmaf(b3.z, w3.z, s); s = fmaf(b3.w, w3.w, s);
    s = fmaf(b4.x, w4.x, s); s = fmaf(b4.y, w4.y, s); s = fmaf(b4.z, w4.z, s); s = fmaf(b4.w, w4.w, s);
    r1 = s;
}
__device__ __forceinline__ float dot4(float4 a, float4 b) {
    float r = a.x * b.x; r = fmaf(a.y, b.y, r); r = fmaf(a.z, b.z, r); r = fmaf(a.w, b.w, r);
    return r;
}

#define FOR20(X) \
  X(0, v0.x) X(1, v0.y) X(2, v0.z) X(3, v0.w) \
  X(4, v1.x) X(5, v1.y) X(6, v1.z) X(7, v1.w) \
  X(8, v2.x) X(9, v2.y) X(10, v2.z) X(11, v2.w) \
  X(12, v3.x) X(13, v3.y) X(14, v3.z) X(15, v3.w) \
  X(16, v4.x) X(17, v4.y) X(18, v4.z) X(19, v4.w)

#define FOR20_2(X) \
  X(0, va0.x, vb0.x) X(1, va0.y, vb0.y) X(2, va0.z, vb0.z) X(3, va0.w, vb0.w) \
  X(4, va1.x, vb1.x) X(5, va1.y, vb1.y) X(6, va1.z, vb1.z) X(7, va1.w, vb1.w) \
  X(8, va2.x, vb2.x) X(9, va2.y, vb2.y) X(10, va2.z, vb2.z) X(11, va2.w, vb2.w) \
  X(12, va3.x, vb3.x) X(13, va3.y, vb3.y) X(14, va3.z, vb3.z) X(15, va3.w, vb3.w) \
  X(16, va4.x, vb4.x) X(17, va4.y, vb4.y) X(18, va4.z, vb4.z) X(19, va4.w, vb4.w)

#define FOR8S2(X) \
  X(0, sa0.x, sb0.x) X(1, sa0.y, sb0.y) X(2, sa0.z, sb0.z) X(3, sa0.w, sb0.w) \
  X(4, sa1.x, sb1.x) X(5, sa1.y, sb1.y) X(6, sa1.z, sb1.z) X(7, sa1.w, sb1.w)

// B[e][o] = sum_f h[e][f] * W1[20+f][o] + b1[o]
__global__ void __launch_bounds__(256) kernel_B(
    const float* __restrict__ h, const float* __restrict__ W1,
    const float* __restrict__ b1, float* __restrict__ B)
{
    __shared__ __align__(16) float sw[640];
    __shared__ __align__(16) float sbias[32];
    for (int i = threadIdx.x; i < 640; i += 256) sw[i] = W1[640 + i];
    if (threadIdx.x < 32) sbias[threadIdx.x] = b1[threadIdx.x];
    __syncthreads();
    int e = blockIdx.x * 256 + threadIdx.x;
    const float4* hp = reinterpret_cast<const float4*>(h + (size_t)e * NF);
    float4 v0 = hp[0], v1 = hp[1], v2 = hp[2], v3 = hp[3], v4 = hp[4];
    const float4* bi = reinterpret_cast<const float4*>(sbias);
    float4 c0 = bi[0], c1 = bi[1], c2 = bi[2], c3 = bi[3],
           c4 = bi[4], c5 = bi[5], c6 = bi[6], c7 = bi[7];
    #define BSTEP(f, hf) { float t_ = (hf); const float4* w_ = (const float4*)&sw[(f)*32]; \
        c0 = f4fma(t_, w_[0], c0); c1 = f4fma(t_, w_[1], c1); \
        c2 = f4fma(t_, w_[2], c2); c3 = f4fma(t_, w_[3], c3); \
        c4 = f4fma(t_, w_[4], c4); c5 = f4fma(t_, w_[5], c5); \
        c6 = f4fma(t_, w_[6], c6); c7 = f4fma(t_, w_[7], c7); }
    FOR20(BSTEP)
    #undef BSTEP
    float4* Bp = reinterpret_cast<float4*>(B + (size_t)e * 32);
    Bp[0] = c0; Bp[1] = c1; Bp[2] = c2; Bp[3] = c3;
    Bp[4] = c4; Bp[5] = c5; Bp[6] = c6; Bp[7] = c7;
}

// One step. 4 lanes per quad, TWO edges per thread (register blocking over
// edges: every LDS weight read feeds 2 edges -> halves DS bytes/edge, which
// was the measured bottleneck: ~260 ds_read_b128/wave ~= 109us of 137us).
__global__ void __launch_bounds__(256) kernel_step(
    const float* __restrict__ h_in, float* __restrict__ h_out,
    const float* __restrict__ B, const int* __restrict__ dst,
    const float* __restrict__ W1, const float* __restrict__ W2, const float* __restrict__ b2,
    const float* __restrict__ Wih, const float* __restrict__ Whh,
    const float* __restrict__ bih, const float* __restrict__ bhh)
{
    __shared__ __align__(16) float sW1[640];   // top 20 rows of msg_W1 (20,32)
    __shared__ __align__(16) float sW2[640];   // (32,20)
    __shared__ __align__(16) float sb2v[20];
    __shared__ __align__(16) float sWih[1200]; // (60,20)
    __shared__ __align__(16) float sWhh[1200];
    __shared__ float sbih[60];
    __shared__ float sbhh[60];
    for (int i = threadIdx.x; i < 640; i += 256) { sW1[i] = W1[i]; sW2[i] = W2[i]; }
    for (int i = threadIdx.x; i < 1200; i += 256) { sWih[i] = Wih[i]; sWhh[i] = Whh[i]; }
    if (threadIdx.x < 20) sb2v[threadIdx.x] = b2[threadIdx.x];
    else if (threadIdx.x >= 64 && threadIdx.x < 124) sbih[threadIdx.x - 64] = bih[threadIdx.x - 64];
    else if (threadIdx.x >= 128 && threadIdx.x < 188) sbhh[threadIdx.x - 128] = bhh[threadIdx.x - 128];
    __syncthreads();

    int t = blockIdx.x * 256 + threadIdx.x;
    int p = t >> 2;                 // edge-pair index
    int q = t & 3;
    int ob = q * 8;
    int e0 = p * 2, e1 = p * 2 + 1;

    int d0 = dst[e0];
    int d1 = dst[e1];

    const float4* hp0 = reinterpret_cast<const float4*>(h_in + (size_t)e0 * NF);
    const float4* hp1 = reinterpret_cast<const float4*>(h_in + (size_t)e1 * NF);
    float4 va0 = hp0[0], va1 = hp0[1], va2 = hp0[2], va3 = hp0[3], va4 = hp0[4];
    float4 vb0 = hp1[0], vb1 = hp1[1], vb2 = hp1[2], vb3 = hp1[3], vb4 = hp1[4];

    // A slices for both edges (shared weight reads)
    float4 aa0 = f4z(), aa1 = f4z(), ab0 = f4z(), ab1 = f4z();
    #define ASTEP2(f, h0, h1) { const float4* w_ = (const float4*)&sW1[(f)*32 + ob]; \
        float4 w0_ = w_[0], w1_ = w_[1]; \
        aa0 = f4fma((h0), w0_, aa0); aa1 = f4fma((h0), w1_, aa1); \
        ab0 = f4fma((h1), w0_, ab0); ab1 = f4fma((h1), w1_, ab1); }
    FOR20_2(ASTEP2)
    #undef ASTEP2

    // gather 16 rows of B for each edge; 4 independent b128 loads per iter
    const float4* Bp0 = reinterpret_cast<const float4*>(B + (size_t)d0 * 512) + (ob >> 2);
    const float4* Bp1 = reinterpret_cast<const float4*>(B + (size_t)d1 * 512) + (ob >> 2);
    float4 sa0 = f4z(), sa1 = f4z(), sb0 = f4z(), sb1 = f4z();
    #pragma unroll 2
    for (int k = 0; k < 16; k++) {
        float4 t00 = Bp0[k * 8 + 0];
        float4 t01 = Bp0[k * 8 + 1];
        float4 t10 = Bp1[k * 8 + 0];
        float4 t11 = Bp1[k * 8 + 1];
        sa0 = f4add(sa0, selu4(f4add(aa0, t00)));
        sa1 = f4add(sa1, selu4(f4add(aa1, t01)));
        sb0 = f4add(sb0, selu4(f4add(ab0, t10)));
        sb1 = f4add(sb1, selu4(f4add(ab1, t11)));
    }

    // partial agg for both edges (shared W2 row reads)
    float4 ga0 = f4z(), ga1 = f4z(), ga2 = f4z(), ga3 = f4z(), ga4 = f4z();
    float4 gb0 = f4z(), gb1 = f4z(), gb2 = f4z(), gb3 = f4z(), gb4 = f4z();
    #define AGGS2(j, c0_, c1_) { const float4* w_ = (const float4*)&sW2[(ob + (j)) * 20]; \
        float4 w0_ = w_[0], w1_ = w_[1], w2_ = w_[2], w3_ = w_[3], w4_ = w_[4]; \
        float u_ = (c0_), v_ = (c1_); \
        ga0 = f4fma(u_, w0_, ga0); ga1 = f4fma(u_, w1_, ga1); ga2 = f4fma(u_, w2_, ga2); \
        ga3 = f4fma(u_, w3_, ga3); ga4 = f4fma(u_, w4_, ga4); \
        gb0 = f4fma(v_, w0_, gb0); gb1 = f4fma(v_, w1_, gb1); gb2 = f4fma(v_, w2_, gb2); \
        gb3 = f4fma(v_, w3_, gb3); gb4 = f4fma(v_, w4_, gb4); }
    FOR8S2(AGGS2)
    #undef AGGS2

    // quad butterfly for both agg sets
    #define BF1(r_, m_) r_.x += __shfl_xor(r_.x, m_); r_.y += __shfl_xor(r_.y, m_); \
                        r_.z += __shfl_xor(r_.z, m_); r_.w += __shfl_xor(r_.w, m_);
    #define BFLY(m_) BF1(ga0, m_) BF1(ga1, m_) BF1(ga2, m_) BF1(ga3, m_) BF1(ga4, m_) \
                     BF1(gb0, m_) BF1(gb1, m_) BF1(gb2, m_) BF1(gb3, m_) BF1(gb4, m_)
    BFLY(1)
    BFLY(2)
    #undef BFLY
    #undef BF1

    {
        const float4* b2p = reinterpret_cast<const float4*>(sb2v);
        float4 c0 = b2p[0], c1 = b2p[1], c2 = b2p[2], c3 = b2p[3], c4 = b2p[4];
        ga0 = f4fma(16.f, c0, ga0); ga1 = f4fma(16.f, c1, ga1); ga2 = f4fma(16.f, c2, ga2);
        ga3 = f4fma(16.f, c3, ga3); ga4 = f4fma(16.f, c4, ga4);
        gb0 = f4fma(16.f, c0, gb0); gb1 = f4fma(16.f, c1, gb1); gb2 = f4fma(16.f, c2, gb2);
        gb3 = f4fma(16.f, c3, gb3); gb4 = f4fma(16.f, c4, gb4);
    }

    // GRU: 5 channels per lane, both edges per weight-row read
    for (int i = 0; i < 5; i++) {
        int c = q * 5 + i;
        float ir0, ir1, iz0, iz1, in0, in1, hr0, hr1, hz0, hz1, hn0, hn1;
        dot20_dual((const float4*)&sWih[c * 20],        ga0, ga1, ga2, ga3, ga4,
                   gb0, gb1, gb2, gb3, gb4, ir0, ir1);
        dot20_dual((const float4*)&sWih[(20 + c) * 20], ga0, ga1, ga2, ga3, ga4,
                   gb0, gb1, gb2, gb3, gb4, iz0, iz1);
        dot20_dual((const float4*)&sWih[(40 + c) * 20], ga0, ga1, ga2, ga3, ga4,
                   gb0, gb1, gb2, gb3, gb4, in0, in1);
        dot20_dual((const float4*)&sWhh[c * 20],        va0, va1, va2, va3, va4,
                   vb0, vb1, vb2, vb3, vb4, hr0, hr1);
        dot20_dual((const float4*)&sWhh[(20 + c) * 20], va0, va1, va2, va3, va4,
                   vb0, vb1, vb2, vb3, vb4, hz0, hz1);
        dot20_dual((const float4*)&sWhh[(40 + c) * 20], va0, va1, va2, va3, va4,
                   vb0, vb1, vb2, vb3, vb4, hn0, hn1);
        float bi_r = sbih[c], bi_z = sbih[20 + c], bi_n = sbih[40 + c];
        float bh_r = sbhh[c], bh_z = sbhh[20 + c], bh_n = sbhh[40 + c];
        // edge 0
        {
            float r = sigmoid_f(bi_r + ir0 + bh_r + hr0);
            float z = sigmoid_f(bi_z + iz0 + bh_z + hz0);
            float xn = bi_n + in0 + r * (bh_n + hn0);
            xn = fminf(fmaxf(xn, -20.f), 20.f);
            float tt = __expf(2.f * xn);
            float n = (tt - 1.f) / (tt + 1.f);
            float hc = h_in[(size_t)e0 * NF + c];
            h_out[(size_t)e0 * NF + c] = (1.f - z) * n + z * hc;
        }
        // edge 1
        {
            float r = sigmoid_f(bi_r + ir1 + bh_r + hr1);
            float z = sigmoid_f(bi_z + iz1 + bh_z + hz1);
            float xn = bi_n + in1 + r * (bh_n + hn1);
            xn = fminf(fmaxf(xn, -20.f), 20.f);
            float tt = __expf(2.f * xn);
            float n = (tt - 1.f) / (tt + 1.f);
            float hc = h_in[(size_t)e1 * NF + c];
            h_out[(size_t)e1 * NF + c] = (1.f - z) * n + z * hc;
        }
    }
}

__global__ void __launch_bounds__(256) kernel_readout(
    const float* __restrict__ h,
    const float* __restrict__ W1, const float* __restrict__ b1,
    const float* __restrict__ W2, const float* __restrict__ b2,
    const float* __restrict__ W3, const float* __restrict__ b3,
    float* __restrict__ out)
{
    __shared__ __align__(16) float sW1t[1280]; // transposed: (64,20)
    __shared__ float sb1[64];
    __shared__ __align__(16) float sW2[2048];  // (64,32)
    __shared__ __align__(16) float sb2v[32];
    __shared__ __align__(16) float sW3[32];
    __shared__ float sb3;
    for (int i = threadIdx.x; i < 1280; i += 256) {
        int f = i >> 6, o = i & 63;
        sW1t[o * 20 + f] = W1[i];
    }
    for (int i = threadIdx.x; i < 2048; i += 256) sW2[i] = W2[i];
    if (threadIdx.x < 64) sb1[threadIdx.x] = b1[threadIdx.x];
    else if (threadIdx.x >= 64 && threadIdx.x < 96) sb2v[threadIdx.x - 64] = b2[threadIdx.x - 64];
    else if (threadIdx.x >= 96 && threadIdx.x < 128) sW3[threadIdx.x - 96] = W3[threadIdx.x - 96];
    if (threadIdx.x == 128) sb3 = b3[0];
    __syncthreads();

    int e = blockIdx.x * 256 + threadIdx.x;
    const float4* hp = reinterpret_cast<const float4*>(h + (size_t)e * NF);
    float4 v0 = hp[0], v1 = hp[1], v2 = hp[2], v3 = hp[3], v4 = hp[4];

    const float4* b2p = reinterpret_cast<const float4*>(sb2v);
    float4 x20 = b2p[0], x21 = b2p[1], x22 = b2p[2], x23 = b2p[3],
           x24 = b2p[4], x25 = b2p[5], x26 = b2p[6], x27 = b2p[7];
    for (int o = 0; o < 64; o++) {
        float x1 = sb1[o] + dot20(v0, v1, v2, v3, v4, (const float4*)&sW1t[o * 20]);
        x1 = selu_f(x1);
        const float4* w = (const float4*)&sW2[o * 32];
        x20 = f4fma(x1, w[0], x20); x21 = f4fma(x1, w[1], x21);
        x22 = f4fma(x1, w[2], x22); x23 = f4fma(x1, w[3], x23);
        x24 = f4fma(x1, w[4], x24); x25 = f4fma(x1, w[5], x25);
        x26 = f4fma(x1, w[6], x26); x27 = f4fma(x1, w[7], x27);
    }
    const float4* w3p = reinterpret_cast<const float4*>(sW3);
    float acc = sb3;
    acc += dot4(selu4(x20), w3p[0]); acc += dot4(selu4(x21), w3p[1]);
    acc += dot4(selu4(x22), w3p[2]); acc += dot4(selu4(x23), w3p[3]);
    acc += dot4(selu4(x24), w3p[4]); acc += dot4(selu4(x25), w3p[5]);
    acc += dot4(selu4(x26), w3p[6]); acc += dot4(selu4(x27), w3p[7]);
    float sp = fmaxf(acc, 0.f) + log1pf(__expf(-fabsf(acc)));
    float w = sp + 0.1f;
    w = fminf(fmaxf(w, 0.1f), 10.f);
    out[e] = w;
}

extern "C" void kernel_launch(void* const* d_in, const int* in_sizes, int n_in,
                              void* d_out, int out_size, void* d_ws, size_t ws_size,
                              hipStream_t stream) {
    const float* edge_attr = (const float*)d_in[0];
    const float* msg_W1   = (const float*)d_in[1];
    const float* msg_b1   = (const float*)d_in[2];
    const float* msg_W2   = (const float*)d_in[3];
    const float* msg_b2   = (const float*)d_in[4];
    const float* gru_Wih  = (const float*)d_in[5];
    const float* gru_Whh  = (const float*)d_in[6];
    const float* gru_bih  = (const float*)d_in[7];
    const float* gru_bhh  = (const float*)d_in[8];
    const float* ro_W1    = (const float*)d_in[9];
    const float* ro_b1    = (const float*)d_in[10];
    const float* ro_W2    = (const float*)d_in[11];
    const float* ro_b2    = (const float*)d_in[12];
    const float* ro_W3    = (const float*)d_in[13];
    const float* ro_b3    = (const float*)d_in[14];
    const int* edge_index = (const int*)d_in[15];
    const int* dst = edge_index + E_EDGES;   // row 1 of (2,E)

    float* h_ws = (float*)d_ws;                       // E*20 floats
    float* Bt   = h_ws + (size_t)E_EDGES * NF;        // E*32 floats

    dim3 gridB(E_EDGES / 256), block(256);
    dim3 gridS(E_EDGES * 2 / 256);     // 4 lanes per edge-pair (2 edges/thread)
    const float* hin = edge_attr;
    for (int s = 0; s < 4; s++) {
        kernel_B<<<gridB, block, 0, stream>>>(hin, msg_W1, msg_b1, Bt);
        kernel_step<<<gridS, block, 0, stream>>>(hin, h_ws, Bt, dst,
            msg_W1, msg_W2, msg_b2, gru_Wih, gru_Whh, gru_bih, gru_bhh);
        hin = h_ws;
    }
    kernel_readout<<<gridB, block, 0, stream>>>(h_ws, ro_W1, ro_b1, ro_W2, ro_b2,
                                                ro_W3, ro_b3, (float*)d_out);
}